// Round 4
// baseline (299.580 us; speedup 1.0000x reference)
//
#include <hip/hip_runtime.h>

#define S_LEN 2048
#define D_MODEL 1024
#define NHEAD 16
#define HDIM 64
#define BATCH 2
#define M_ROWS (BATCH * S_LEN)   // 4096
#define N_QKV (3 * D_MODEL)      // 3072
#define QSCALE 0.18033688011112042f  // 0.125 * log2(e)

typedef __attribute__((ext_vector_type(8))) short bf16x8;
typedef __attribute__((ext_vector_type(4))) float f32x4;

static __device__ __forceinline__ unsigned short f2bf(float f) {
  unsigned int u = __float_as_uint(f);
  u += 0x7FFFu + ((u >> 16) & 1u);   // RNE
  return (unsigned short)(u >> 16);
}
// pack two floats to bf16x2 (round-half-up: +0x8000 then take hi16 via v_perm)
static __device__ __forceinline__ unsigned int pkbf(float a, float b) {
  unsigned int ua = __float_as_uint(a) + 0x8000u;
  unsigned int ub = __float_as_uint(b) + 0x8000u;
  return __builtin_amdgcn_perm(ub, ua, 0x07060302u);
}

// async global->LDS 16B copy (wave-uniform LDS base + lane*16 layout required)
static __device__ __forceinline__ void async_cp16(unsigned short* lds, const unsigned short* g) {
  __builtin_amdgcn_global_load_lds((__attribute__((address_space(1))) void*)g,
                                   (__attribute__((address_space(3))) void*)lds, 16, 0, 0);
}

// ---------------- cast fp32 -> bf16 (vectorized x4) ----------------
__global__ __launch_bounds__(256) void k_cast4(const float* __restrict__ x,
                                               unsigned short* __restrict__ y, int n4) {
  int i = blockIdx.x * 256 + threadIdx.x;
  if (i >= n4) return;
  float4 v = ((const float4*)x)[i];
  ushort4 o;
  o.x = f2bf(v.x); o.y = f2bf(v.y); o.z = f2bf(v.z); o.w = f2bf(v.w);
  ((ushort4*)y)[i] = o;
}

// ------------- transpose + cast: w[K][N] fp32 -> wT[N][K] bf16 -------------
__global__ __launch_bounds__(256) void k_transcast(const float* __restrict__ w,
                                                   unsigned short* __restrict__ wT,
                                                   int Kdim, int Ndim) {
  __shared__ unsigned short T[32][33];
  int n0 = blockIdx.x * 32, k0 = blockIdx.y * 32;
  int tx = threadIdx.x & 31, ty = threadIdx.x >> 5;
#pragma unroll
  for (int j = 0; j < 4; ++j) {
    int r = ty + j * 8;
    T[r][tx] = f2bf(w[(size_t)(k0 + r) * Ndim + n0 + tx]);
  }
  __syncthreads();
#pragma unroll
  for (int j = 0; j < 4; ++j) {
    int r = ty + j * 8;
    wT[(size_t)(n0 + r) * Kdim + k0 + tx] = T[tx][r];
  }
}

// ---------------- QKV GEMM: [4096,1024] x [1024,3072] + bias ----------------
// Q stored TRANSPOSED [bh][d][s] with 0.125*log2e folded in; K row-major; V transposed.
__global__ __launch_bounds__(256) void k_gemm_qkv(const unsigned short* __restrict__ A,
                                                  const unsigned short* __restrict__ Bt,
                                                  const float* __restrict__ bias,
                                                  unsigned short* __restrict__ QTb,
                                                  unsigned short* __restrict__ Kbuf,
                                                  unsigned short* __restrict__ VTb) {
  __shared__ __align__(16) unsigned short As[128 * 32];
  __shared__ __align__(16) unsigned short Bs[128 * 32];
  const int tid = threadIdx.x;
  const int wid = tid >> 6, lane = tid & 63;
  const int lr = lane & 15, lg = lane >> 4;
  const int bm = blockIdx.y * 128, bn = blockIdx.x * 128;
  const int wm = (wid >> 1) * 64, wn = (wid & 1) * 64;
  const int K = D_MODEL;
  const int c0 = tid, c1 = tid + 256;   // 16B chunks: row = c>>2, kchunk = c&3
  const size_t a0o = (size_t)(bm + (c0 >> 2)) * K + (c0 & 3) * 8;
  const size_t a1o = (size_t)(bm + (c1 >> 2)) * K + (c1 & 3) * 8;
  const size_t b0o = (size_t)(bn + (c0 >> 2)) * K + (c0 & 3) * 8;
  const size_t b1o = (size_t)(bn + (c1 >> 2)) * K + (c1 & 3) * 8;

  f32x4 acc[4][4] = {};

  for (int k0 = 0; k0 < K; k0 += 32) {
    __syncthreads();
    async_cp16(&As[c0 * 8], &A[a0o + k0]);
    async_cp16(&As[c1 * 8], &A[a1o + k0]);
    async_cp16(&Bs[c0 * 8], &Bt[b0o + k0]);
    async_cp16(&Bs[c1 * 8], &Bt[b1o + k0]);
    __syncthreads();
    bf16x8 af[4], bfr[4];
#pragma unroll
    for (int i = 0; i < 4; ++i) af[i] = *(const bf16x8*)&As[(wm + i * 16 + lr) * 32 + lg * 8];
#pragma unroll
    for (int t = 0; t < 4; ++t) bfr[t] = *(const bf16x8*)&Bs[(wn + t * 16 + lr) * 32 + lg * 8];
#pragma unroll
    for (int i = 0; i < 4; ++i)
#pragma unroll
      for (int t = 0; t < 4; ++t)
        acc[i][t] = __builtin_amdgcn_mfma_f32_16x16x32_bf16(af[i], bfr[t], acc[i][t], 0, 0, 0);
  }
  // epilogue: Q^T (scaled) & V^T as ushort4 along s; K row-major scalar
#pragma unroll
  for (int i = 0; i < 4; ++i) {
#pragma unroll
    for (int t = 0; t < 4; ++t) {
      int n = bn + wn + t * 16 + lr;
      int part = n >> 10, rem = n & 1023;
      int h = rem >> 6, d = rem & 63;
      float bv = bias[n];
      int row0 = bm + wm + i * 16 + lg * 4;
      int bb = row0 >> 11, s0 = row0 & 2047;   // 4 rows never cross batch boundary
      if (part == 1) {
#pragma unroll
        for (int r = 0; r < 4; ++r)
          Kbuf[(((size_t)(bb << 4) + h) * S_LEN + (s0 + r)) * HDIM + d] = f2bf(acc[i][t][r] + bv);
      } else {
        float sc = (part == 0) ? QSCALE : 1.0f;
        unsigned short* dstT = (part == 0) ? QTb : VTb;
        ushort4 vv;
        vv.x = f2bf((acc[i][t][0] + bv) * sc);
        vv.y = f2bf((acc[i][t][1] + bv) * sc);
        vv.z = f2bf((acc[i][t][2] + bv) * sc);
        vv.w = f2bf((acc[i][t][3] + bv) * sc);
        *(ushort4*)&dstT[(((size_t)(bb << 4) + h) * HDIM + d) * S_LEN + s0] = vv;
      }
    }
  }
}

// ---------------- Proj GEMM: [4096,1024] x [1024,1024] + bias -> fp32 ----------------
__global__ __launch_bounds__(256) void k_gemm_proj(const unsigned short* __restrict__ A,
                                                   const unsigned short* __restrict__ Bt,
                                                   const float* __restrict__ bias,
                                                   float* __restrict__ out) {
  __shared__ __align__(16) unsigned short As[128 * 32];
  __shared__ __align__(16) unsigned short Bs[128 * 32];
  const int tid = threadIdx.x;
  const int wid = tid >> 6, lane = tid & 63;
  const int lr = lane & 15, lg = lane >> 4;
  const int bm = blockIdx.y * 128, bn = blockIdx.x * 128;
  const int wm = (wid >> 1) * 64, wn = (wid & 1) * 64;
  const int K = D_MODEL;
  const int c0 = tid, c1 = tid + 256;
  const size_t a0o = (size_t)(bm + (c0 >> 2)) * K + (c0 & 3) * 8;
  const size_t a1o = (size_t)(bm + (c1 >> 2)) * K + (c1 & 3) * 8;
  const size_t b0o = (size_t)(bn + (c0 >> 2)) * K + (c0 & 3) * 8;
  const size_t b1o = (size_t)(bn + (c1 >> 2)) * K + (c1 & 3) * 8;

  f32x4 acc[4][4] = {};

  for (int k0 = 0; k0 < K; k0 += 32) {
    __syncthreads();
    async_cp16(&As[c0 * 8], &A[a0o + k0]);
    async_cp16(&As[c1 * 8], &A[a1o + k0]);
    async_cp16(&Bs[c0 * 8], &Bt[b0o + k0]);
    async_cp16(&Bs[c1 * 8], &Bt[b1o + k0]);
    __syncthreads();
    bf16x8 af[4], bfr[4];
#pragma unroll
    for (int i = 0; i < 4; ++i) af[i] = *(const bf16x8*)&As[(wm + i * 16 + lr) * 32 + lg * 8];
#pragma unroll
    for (int t = 0; t < 4; ++t) bfr[t] = *(const bf16x8*)&Bs[(wn + t * 16 + lr) * 32 + lg * 8];
#pragma unroll
    for (int i = 0; i < 4; ++i)
#pragma unroll
      for (int t = 0; t < 4; ++t)
        acc[i][t] = __builtin_amdgcn_mfma_f32_16x16x32_bf16(af[i], bfr[t], acc[i][t], 0, 0, 0);
  }
#pragma unroll
  for (int i = 0; i < 4; ++i) {
#pragma unroll
    for (int t = 0; t < 4; ++t) {
      int n = bn + wn + t * 16 + lr;
      float bv = bias[n];
#pragma unroll
      for (int r = 0; r < 4; ++r) {
        int row = bm + wm + i * 16 + lg * 4 + r;
        out[(size_t)row * D_MODEL + n] = acc[i][t][r] + bv;
      }
    }
  }
}

// ---------------- Flash attention round 4: 1-wave workgroups ----------------
// 16-row strips, wave-autonomous S^T/O^T, balanced pairing (strip w & 127-w).
// 64-thread blocks -> 16 resident waves/CU (vs 8) to hide the serial
// load->MFMA->softmax->LDS chain. bh on blockIdx.x pins bh to XCD bh%8 so
// each XCD L2 holds only 4 bh of K/V (2 MB, fits).
#define ATTN_TILE(KCUR, KNXT)                                                         \
  {                                                                                   \
    _Pragma("unroll") for (int dg = 0; dg < 4; ++dg)                                  \
      _Pragma("unroll") for (int kh = 0; kh < 2; ++kh)                                \
        vf[dg][kh] = *(const bf16x8*)&VTbh[(size_t)(dg * 16 + lr) * S_LEN + k0 +      \
                                           kh * 32 + quad * 8];                       \
    const int k0n = (k0 == lastk0) ? k0 : k0 + 64;                                    \
    _Pragma("unroll") for (int kg = 0; kg < 4; ++kg)                                  \
      _Pragma("unroll") for (int dh = 0; dh < 2; ++dh)                                \
        KNXT[kg][dh] = *(const bf16x8*)&Kbh[(size_t)(k0n + kg * 16 + lr) * HDIM +     \
                                            dh * 32 + quad * 8];                      \
    f32x4 Sv[4];                                                                      \
    _Pragma("unroll") for (int kg = 0; kg < 4; ++kg) {                                \
      f32x4 a = {};                                                                   \
      a = __builtin_amdgcn_mfma_f32_16x16x32_bf16(KCUR[kg][0], qf0, a, 0, 0, 0);      \
      a = __builtin_amdgcn_mfma_f32_16x16x32_bf16(KCUR[kg][1], qf1, a, 0, 0, 0);      \
      Sv[kg] = a;                                                                     \
    }                                                                                 \
    if (k0 == lastk0) { /* diagonal tile: causal mask */                              \
      const int q = R + lr;                                                           \
      _Pragma("unroll") for (int kg = 0; kg < 4; ++kg)                                \
        _Pragma("unroll") for (int r = 0; r < 4; ++r)                                 \
          if (k0 + kg * 16 + quad * 4 + r > q) Sv[kg][r] = -1e30f;                    \
    }                                                                                 \
    float mx = m;                                                                     \
    _Pragma("unroll") for (int kg = 0; kg < 4; ++kg)                                  \
      mx = fmaxf(mx, fmaxf(fmaxf(Sv[kg][0], Sv[kg][1]), fmaxf(Sv[kg][2], Sv[kg][3])));\
    mx = fmaxf(mx, __shfl_xor(mx, 16));                                               \
    mx = fmaxf(mx, __shfl_xor(mx, 32));                                               \
    const float alpha = __builtin_amdgcn_exp2f(m - mx);                               \
    m = mx;                                                                           \
    float rs = 0.f;                                                                   \
    _Pragma("unroll") for (int kg = 0; kg < 4; ++kg) {                                \
      float e0 = __builtin_amdgcn_exp2f(Sv[kg][0] - mx);                              \
      float e1 = __builtin_amdgcn_exp2f(Sv[kg][1] - mx);                              \
      float e2 = __builtin_amdgcn_exp2f(Sv[kg][2] - mx);                              \
      float e3 = __builtin_amdgcn_exp2f(Sv[kg][3] - mx);                              \
      rs += (e0 + e1) + (e2 + e3);                                                    \
      *(unsigned int*)&pb[lr * 72 + kg * 16 + quad * 4] = pkbf(e0, e1);               \
      *(unsigned int*)&pb[lr * 72 + kg * 16 + quad * 4 + 2] = pkbf(e2, e3);           \
    }                                                                                 \
    rs += __shfl_xor(rs, 16);                                                         \
    rs += __shfl_xor(rs, 32);                                                         \
    l = l * alpha + rs;                                                               \
    _Pragma("unroll") for (int dg = 0; dg < 4; ++dg)                                  \
      _Pragma("unroll") for (int r = 0; r < 4; ++r) Ot[dg][r] *= alpha;               \
    bf16x8 pf0 = *(const bf16x8*)&pb[lr * 72 + quad * 8];                             \
    bf16x8 pf1 = *(const bf16x8*)&pb[lr * 72 + 32 + quad * 8];                        \
    _Pragma("unroll") for (int dg = 0; dg < 4; ++dg) {                                \
      Ot[dg] = __builtin_amdgcn_mfma_f32_16x16x32_bf16(vf[dg][0], pf0, Ot[dg], 0, 0, 0); \
      Ot[dg] = __builtin_amdgcn_mfma_f32_16x16x32_bf16(vf[dg][1], pf1, Ot[dg], 0, 0, 0); \
    }                                                                                 \
  }

static __device__ __forceinline__ void attn_strip(int R, int bh, int lr, int quad,
                                                  const unsigned short* __restrict__ QTbh,
                                                  const unsigned short* __restrict__ Kbh,
                                                  const unsigned short* __restrict__ VTbh,
                                                  unsigned short* __restrict__ AO,
                                                  unsigned short* __restrict__ pb) {
  const int b = bh >> 4, h = bh & 15;
  // Q fragments from Q^T[d][s]: B-operand lane holds Q[q=lr][d = (dh*32)+quad*8+j]
  bf16x8 qf0, qf1;
#pragma unroll
  for (int j = 0; j < 8; ++j) {
    qf0[j] = (short)QTbh[(size_t)(quad * 8 + j) * S_LEN + R + lr];
    qf1[j] = (short)QTbh[(size_t)(32 + quad * 8 + j) * S_LEN + R + lr];
  }
  f32x4 Ot[4] = {};
  float m = -1e30f, l = 0.f;
  const int lastk0 = R & ~63;
  bf16x8 kfa[4][2], kfb[4][2], vf[4][2];
#pragma unroll
  for (int kg = 0; kg < 4; ++kg)
#pragma unroll
    for (int dh = 0; dh < 2; ++dh)
      kfa[kg][dh] = *(const bf16x8*)&Kbh[(size_t)(kg * 16 + lr) * HDIM + dh * 32 + quad * 8];
  int k0 = 0;
  for (;;) {
    ATTN_TILE(kfa, kfb)
    if (k0 == lastk0) break;
    k0 += 64;
    ATTN_TILE(kfb, kfa)
    if (k0 == lastk0) break;
    k0 += 64;
  }
  const float rl = __builtin_amdgcn_rcpf(l);
  const int s = R + lr;
#pragma unroll
  for (int dg = 0; dg < 4; ++dg) {
    const size_t o = ((size_t)b * S_LEN + s) * D_MODEL + h * 64 + dg * 16 + quad * 4;
    *(unsigned int*)&AO[o]     = pkbf(Ot[dg][0] * rl, Ot[dg][1] * rl);
    *(unsigned int*)&AO[o + 2] = pkbf(Ot[dg][2] * rl, Ot[dg][3] * rl);
  }
}

__global__ __launch_bounds__(64, 4) void k_attn4(const unsigned short* __restrict__ QT,
                                                 const unsigned short* __restrict__ Kb,
                                                 const unsigned short* __restrict__ VT,
                                                 unsigned short* __restrict__ AO) {
  const int lane = threadIdx.x;
  const int lr = lane & 15, quad = lane >> 4;
  const int bh = blockIdx.x;      // bh -> XCD bh%8 (L2 locality)
  const int wslot = blockIdx.y;   // 0..63

  __shared__ __align__(16) unsigned short Pbuf[16 * 72];

  const unsigned short* QTbh = QT + (size_t)bh * HDIM * S_LEN;
  const unsigned short* Kbh = Kb + (size_t)bh * S_LEN * HDIM;
  const unsigned short* VTbh = VT + (size_t)bh * HDIM * S_LEN;

  attn_strip((127 - wslot) * 16, bh, lr, quad, QTbh, Kbh, VTbh, AO, Pbuf);  // heavy
  attn_strip(wslot * 16, bh, lr, quad, QTbh, Kbh, VTbh, AO, Pbuf);          // light
}

extern "C" void kernel_launch(void* const* d_in, const int* in_sizes, int n_in,
                              void* d_out, int out_size, void* d_ws, size_t ws_size,
                              hipStream_t stream) {
  const float* x      = (const float*)d_in[0];
  const float* w_attn = (const float*)d_in[1];
  const float* b_attn = (const float*)d_in[2];
  const float* w_proj = (const float*)d_in[3];
  const float* b_proj = (const float*)d_in[4];
  float* out = (float*)d_out;

  unsigned short* ws     = (unsigned short*)d_ws;
  unsigned short* xb     = ws;                                   // 4096x1024
  unsigned short* wqkvT  = xb + (size_t)M_ROWS * D_MODEL;        // 3072x1024
  unsigned short* wprojT = wqkvT + (size_t)N_QKV * D_MODEL;      // 1024x1024
  unsigned short* QT     = wprojT + (size_t)D_MODEL * D_MODEL;   // [B*H, hd, S] (pre-scaled)
  unsigned short* Kb     = QT + (size_t)M_ROWS * D_MODEL;        // [B*H, S, hd]
  unsigned short* VT     = Kb + (size_t)M_ROWS * D_MODEL;        // [B*H, hd, S]
  unsigned short* AO     = xb;  // reuse: xb dead after QKV GEMM

  int n4 = M_ROWS * D_MODEL / 4;
  k_cast4<<<(n4 + 255) / 256, 256, 0, stream>>>(x, xb, n4);
  k_transcast<<<dim3(N_QKV / 32, D_MODEL / 32), 256, 0, stream>>>(w_attn, wqkvT, D_MODEL, N_QKV);
  k_transcast<<<dim3(D_MODEL / 32, D_MODEL / 32), 256, 0, stream>>>(w_proj, wprojT, D_MODEL, D_MODEL);
  k_gemm_qkv<<<dim3(N_QKV / 128, M_ROWS / 128), 256, 0, stream>>>(xb, wqkvT, b_attn, QT, Kb, VT);
  k_attn4<<<dim3(BATCH * NHEAD, 64), 64, 0, stream>>>(QT, Kb, VT, AO);
  k_gemm_proj<<<dim3(D_MODEL / 128, M_ROWS / 128), 256, 0, stream>>>(AO, wprojT, b_proj, out);
}

// Round 5
// 199.445 us; speedup vs baseline: 1.5021x; 1.5021x over previous
//
#include <hip/hip_runtime.h>

#define S_LEN 2048
#define D_MODEL 1024
#define NHEAD 16
#define HDIM 64
#define BATCH 2
#define M_ROWS (BATCH * S_LEN)   // 4096
#define N_QKV (3 * D_MODEL)      // 3072
#define QSCALE 0.18033688011112042f  // 0.125 * log2(e)

typedef __attribute__((ext_vector_type(8))) short bf16x8;
typedef __attribute__((ext_vector_type(4))) float f32x4;

static __device__ __forceinline__ unsigned short f2bf(float f) {
  unsigned int u = __float_as_uint(f);
  u += 0x7FFFu + ((u >> 16) & 1u);   // RNE
  return (unsigned short)(u >> 16);
}
// pack two floats to bf16x2
static __device__ __forceinline__ unsigned int pkbf(float a, float b) {
  unsigned int ua = __float_as_uint(a) + 0x8000u;
  unsigned int ub = __float_as_uint(b) + 0x8000u;
  return __builtin_amdgcn_perm(ub, ua, 0x07060302u);
}

// async global->LDS 16B copy; effective LDS dst = wave-uniform base + lane*16
static __device__ __forceinline__ void async_cp16(unsigned short* lds, const unsigned short* g) {
  __builtin_amdgcn_global_load_lds((__attribute__((address_space(1))) void*)g,
                                   (__attribute__((address_space(3))) void*)lds, 16, 0, 0);
}

// ---------------- merged prep: cast x, transpose-cast both weights ----------------
// blocks [0,4096): cast x; [4096,7168): w_attn transcast; [7168,8192): w_proj transcast
__global__ __launch_bounds__(256) void k_prep(const float* __restrict__ x,
                                              unsigned short* __restrict__ xb,
                                              const float* __restrict__ w_attn,
                                              unsigned short* __restrict__ wqkvT,
                                              const float* __restrict__ w_proj,
                                              unsigned short* __restrict__ wprojT) {
  __shared__ unsigned short T[32][33];
  const int blk = blockIdx.x;
  const int tid = threadIdx.x;
  if (blk < 4096) {
    int i = blk * 256 + tid;
    float4 v = ((const float4*)x)[i];
    ushort4 o;
    o.x = f2bf(v.x); o.y = f2bf(v.y); o.z = f2bf(v.z); o.w = f2bf(v.w);
    ((ushort4*)xb)[i] = o;
    return;
  }
  const float* w;
  unsigned short* wT;
  int bid, Ndim;
  if (blk < 7168) { bid = blk - 4096; w = w_attn; wT = wqkvT; Ndim = N_QKV; }
  else            { bid = blk - 7168; w = w_proj; wT = wprojT; Ndim = D_MODEL; }
  const int nb = Ndim / 32;
  const int n0 = (bid % nb) * 32, k0 = (bid / nb) * 32;
  const int tx = tid & 31, ty = tid >> 5;
#pragma unroll
  for (int j = 0; j < 4; ++j) {
    int r = ty + j * 8;
    T[r][tx] = f2bf(w[(size_t)(k0 + r) * Ndim + n0 + tx]);
  }
  __syncthreads();
#pragma unroll
  for (int j = 0; j < 4; ++j) {
    int r = ty + j * 8;
    wT[(size_t)(n0 + r) * D_MODEL + k0 + tx] = T[tx][r];
  }
}

// ---------------- QKV GEMM: [4096,1024] x [1024,3072] + bias ----------------
// Q scaled by 0.125*log2(e); K row-major; V transposed [bh][d][s].
__global__ __launch_bounds__(256) void k_gemm_qkv(const unsigned short* __restrict__ A,
                                                  const unsigned short* __restrict__ Bt,
                                                  const float* __restrict__ bias,
                                                  unsigned short* __restrict__ Qb,
                                                  unsigned short* __restrict__ Kbuf,
                                                  unsigned short* __restrict__ VTb) {
  __shared__ __align__(16) unsigned short As[128 * 32];
  __shared__ __align__(16) unsigned short Bs[128 * 32];
  const int tid = threadIdx.x;
  const int wid = tid >> 6, lane = tid & 63;
  const int lr = lane & 15, lg = lane >> 4;
  const int bm = blockIdx.y * 128, bn = blockIdx.x * 128;
  const int wm = (wid >> 1) * 64, wn = (wid & 1) * 64;
  const int K = D_MODEL;
  const int c0 = tid, c1 = tid + 256;
  const size_t a0o = (size_t)(bm + (c0 >> 2)) * K + (c0 & 3) * 8;
  const size_t a1o = (size_t)(bm + (c1 >> 2)) * K + (c1 & 3) * 8;
  const size_t b0o = (size_t)(bn + (c0 >> 2)) * K + (c0 & 3) * 8;
  const size_t b1o = (size_t)(bn + (c1 >> 2)) * K + (c1 & 3) * 8;

  f32x4 acc[4][4] = {};

  for (int k0 = 0; k0 < K; k0 += 32) {
    __syncthreads();
    async_cp16(&As[c0 * 8], &A[a0o + k0]);
    async_cp16(&As[c1 * 8], &A[a1o + k0]);
    async_cp16(&Bs[c0 * 8], &Bt[b0o + k0]);
    async_cp16(&Bs[c1 * 8], &Bt[b1o + k0]);
    __syncthreads();
    bf16x8 af[4], bfr[4];
#pragma unroll
    for (int i = 0; i < 4; ++i) af[i] = *(const bf16x8*)&As[(wm + i * 16 + lr) * 32 + lg * 8];
#pragma unroll
    for (int t = 0; t < 4; ++t) bfr[t] = *(const bf16x8*)&Bs[(wn + t * 16 + lr) * 32 + lg * 8];
#pragma unroll
    for (int i = 0; i < 4; ++i)
#pragma unroll
      for (int t = 0; t < 4; ++t)
        acc[i][t] = __builtin_amdgcn_mfma_f32_16x16x32_bf16(af[i], bfr[t], acc[i][t], 0, 0, 0);
  }
#pragma unroll
  for (int i = 0; i < 4; ++i) {
#pragma unroll
    for (int t = 0; t < 4; ++t) {
      int n = bn + wn + t * 16 + lr;
      int part = n >> 10, rem = n & 1023;
      int h = rem >> 6, d = rem & 63;
      float bv = bias[n];
      int row0 = bm + wm + i * 16 + lg * 4;
      int bb = row0 >> 11, s0 = row0 & 2047;
      if (part == 2) {
        ushort4 vv;
        vv.x = f2bf(acc[i][t][0] + bv);
        vv.y = f2bf(acc[i][t][1] + bv);
        vv.z = f2bf(acc[i][t][2] + bv);
        vv.w = f2bf(acc[i][t][3] + bv);
        *(ushort4*)&VTb[(((size_t)(bb << 4) + h) * HDIM + d) * S_LEN + s0] = vv;
      } else {
        unsigned short* dst = (part == 0) ? Qb : Kbuf;
        float sc = (part == 0) ? QSCALE : 1.0f;
#pragma unroll
        for (int r = 0; r < 4; ++r)
          dst[(((size_t)(bb << 4) + h) * S_LEN + (s0 + r)) * HDIM + d] = f2bf((acc[i][t][r] + bv) * sc);
      }
    }
  }
}

// ---------------- Proj GEMM: [4096,1024] x [1024,1024] + bias -> fp32 ----------------
__global__ __launch_bounds__(256) void k_gemm_proj(const unsigned short* __restrict__ A,
                                                   const unsigned short* __restrict__ Bt,
                                                   const float* __restrict__ bias,
                                                   float* __restrict__ out) {
  __shared__ __align__(16) unsigned short As[128 * 32];
  __shared__ __align__(16) unsigned short Bs[128 * 32];
  const int tid = threadIdx.x;
  const int wid = tid >> 6, lane = tid & 63;
  const int lr = lane & 15, lg = lane >> 4;
  const int bm = blockIdx.y * 128, bn = blockIdx.x * 128;
  const int wm = (wid >> 1) * 64, wn = (wid & 1) * 64;
  const int K = D_MODEL;
  const int c0 = tid, c1 = tid + 256;
  const size_t a0o = (size_t)(bm + (c0 >> 2)) * K + (c0 & 3) * 8;
  const size_t a1o = (size_t)(bm + (c1 >> 2)) * K + (c1 & 3) * 8;
  const size_t b0o = (size_t)(bn + (c0 >> 2)) * K + (c0 & 3) * 8;
  const size_t b1o = (size_t)(bn + (c1 >> 2)) * K + (c1 & 3) * 8;

  f32x4 acc[4][4] = {};

  for (int k0 = 0; k0 < K; k0 += 32) {
    __syncthreads();
    async_cp16(&As[c0 * 8], &A[a0o + k0]);
    async_cp16(&As[c1 * 8], &A[a1o + k0]);
    async_cp16(&Bs[c0 * 8], &Bt[b0o + k0]);
    async_cp16(&Bs[c1 * 8], &Bt[b1o + k0]);
    __syncthreads();
    bf16x8 af[4], bfr[4];
#pragma unroll
    for (int i = 0; i < 4; ++i) af[i] = *(const bf16x8*)&As[(wm + i * 16 + lr) * 32 + lg * 8];
#pragma unroll
    for (int t = 0; t < 4; ++t) bfr[t] = *(const bf16x8*)&Bs[(wn + t * 16 + lr) * 32 + lg * 8];
#pragma unroll
    for (int i = 0; i < 4; ++i)
#pragma unroll
      for (int t = 0; t < 4; ++t)
        acc[i][t] = __builtin_amdgcn_mfma_f32_16x16x32_bf16(af[i], bfr[t], acc[i][t], 0, 0, 0);
  }
#pragma unroll
  for (int i = 0; i < 4; ++i) {
#pragma unroll
    for (int t = 0; t < 4; ++t) {
      int n = bn + wn + t * 16 + lr;
      float bv = bias[n];
#pragma unroll
      for (int r = 0; r < 4; ++r) {
        int row = bm + wm + i * 16 + lg * 4 + r;
        out[(size_t)row * D_MODEL + n] = acc[i][t][r] + bv;
      }
    }
  }
}

// ---------------- Flash attention round 5: block-cooperative LDS staging ----------------
// Block = 4 waves; stages K-tile[64 keys][64 d] and V^T-tile[64 d][64 s] into LDS
// via global_load_lds (xor-swizzled 16B blocks so b128 fragment reads hit all banks).
// Wave wid fuses balanced strip pair (sL = slot*4+wid, sH = 127-sL) in one tile loop.
// S^T/O^T math identical to round 3 (verified).
__global__ __launch_bounds__(256, 2) void k_attn6(const unsigned short* __restrict__ Qb,
                                                  const unsigned short* __restrict__ Kb,
                                                  const unsigned short* __restrict__ VT,
                                                  unsigned short* __restrict__ AO) {
  const int tid = threadIdx.x;
  const int wid = tid >> 6, lane = tid & 63;
  const int lr = lane & 15, quad = lane >> 4;
  const int bh = blockIdx.x;                  // XCD pin: bh % 8
  const int slot = blockIdx.y;                // 0..15
  const int b = bh >> 4, h = bh & 15;

  __shared__ __align__(16) unsigned short Ks[64 * 64];
  __shared__ __align__(16) unsigned short Vs[64 * 64];
  __shared__ __align__(16) unsigned short Pbuf[4][16 * 72];
  unsigned short* pb = &Pbuf[wid][0];

  const unsigned short* Kbh = Kb + (size_t)bh * S_LEN * HDIM;
  const unsigned short* VTbh = VT + (size_t)bh * HDIM * S_LEN;

  const int sL = slot * 4 + wid;              // 0..63
  const int Rs[2] = {sL * 16, (127 - sL) * 16};
  const int ntile = ((127 - slot * 4) >> 2) + 1;   // block trip count (heaviest wave)

  // Q fragments for both strips (row-major Q, pre-scaled)
  bf16x8 qf[2][2];
#pragma unroll
  for (int st = 0; st < 2; ++st)
#pragma unroll
    for (int dh = 0; dh < 2; ++dh)
      qf[st][dh] = *(const bf16x8*)&Qb[((size_t)bh * S_LEN + Rs[st] + lr) * HDIM + dh * 32 + quad * 8];

  f32x4 Ot[2][4] = {};
  float ms[2] = {-1e30f, -1e30f};
  float ls[2] = {0.f, 0.f};

  // staging lane constants: lane covers (srow, swizzled 16B block)
  const int srow = lane >> 3;                       // 0..7
  const int scol = ((lane & 7) ^ srow) * 8;         // element offset, xor-swizzled

  for (int kt = 0; kt < ntile; ++kt) {
    const int k0 = kt * 64;
    __syncthreads();   // previous tile's ds_reads done
#pragma unroll
    for (int j = 0; j < 2; ++j) {
      const int r0 = wid * 16 + j * 8;
      async_cp16(&Ks[r0 * 64 + lane * 8], &Kbh[(size_t)(k0 + r0 + srow) * HDIM + scol]);
      async_cp16(&Vs[r0 * 64 + lane * 8], &VTbh[(size_t)(r0 + srow) * S_LEN + k0 + scol]);
    }
    __syncthreads();   // staged (barrier drains vmcnt)

    bf16x8 kf[4][2], vf[4][2];
#pragma unroll
    for (int kg = 0; kg < 4; ++kg)
#pragma unroll
      for (int dh = 0; dh < 2; ++dh)
        kf[kg][dh] = *(const bf16x8*)&Ks[(kg * 16 + lr) * 64 + (((dh * 4 + quad) ^ (lr & 7)) * 8)];
#pragma unroll
    for (int dg = 0; dg < 4; ++dg)
#pragma unroll
      for (int kh = 0; kh < 2; ++kh)
        vf[dg][kh] = *(const bf16x8*)&Vs[(dg * 16 + lr) * 64 + (((kh * 4 + quad) ^ (lr & 7)) * 8)];

#pragma unroll
    for (int st = 0; st < 2; ++st) {
      const int R = Rs[st];
      if (k0 > R + 15) continue;    // strip finished (wave-uniform branch)
      f32x4 Sv[4];
#pragma unroll
      for (int kg = 0; kg < 4; ++kg) {
        f32x4 a = {};
        a = __builtin_amdgcn_mfma_f32_16x16x32_bf16(kf[kg][0], qf[st][0], a, 0, 0, 0);
        a = __builtin_amdgcn_mfma_f32_16x16x32_bf16(kf[kg][1], qf[st][1], a, 0, 0, 0);
        Sv[kg] = a;
      }
      if (k0 + 63 > R) {            // diagonal tile: causal mask
        const int q = R + lr;
#pragma unroll
        for (int kg = 0; kg < 4; ++kg)
#pragma unroll
          for (int r = 0; r < 4; ++r)
            if (k0 + kg * 16 + quad * 4 + r > q) Sv[kg][r] = -1e30f;
      }
      float mx = ms[st];
#pragma unroll
      for (int kg = 0; kg < 4; ++kg)
        mx = fmaxf(mx, fmaxf(fmaxf(Sv[kg][0], Sv[kg][1]), fmaxf(Sv[kg][2], Sv[kg][3])));
      mx = fmaxf(mx, __shfl_xor(mx, 16));
      mx = fmaxf(mx, __shfl_xor(mx, 32));
      const float alpha = __builtin_amdgcn_exp2f(ms[st] - mx);
      ms[st] = mx;
      float rs = 0.f;
#pragma unroll
      for (int kg = 0; kg < 4; ++kg) {
        float e0 = __builtin_amdgcn_exp2f(Sv[kg][0] - mx);
        float e1 = __builtin_amdgcn_exp2f(Sv[kg][1] - mx);
        float e2 = __builtin_amdgcn_exp2f(Sv[kg][2] - mx);
        float e3 = __builtin_amdgcn_exp2f(Sv[kg][3] - mx);
        rs += (e0 + e1) + (e2 + e3);
        *(unsigned int*)&pb[lr * 72 + kg * 16 + quad * 4]     = pkbf(e0, e1);
        *(unsigned int*)&pb[lr * 72 + kg * 16 + quad * 4 + 2] = pkbf(e2, e3);
      }
      rs += __shfl_xor(rs, 16);
      rs += __shfl_xor(rs, 32);
      ls[st] = ls[st] * alpha + rs;
#pragma unroll
      for (int dg = 0; dg < 4; ++dg)
#pragma unroll
        for (int r = 0; r < 4; ++r) Ot[st][dg][r] *= alpha;
      bf16x8 pf0 = *(const bf16x8*)&pb[lr * 72 + quad * 8];
      bf16x8 pf1 = *(const bf16x8*)&pb[lr * 72 + 32 + quad * 8];
#pragma unroll
      for (int dg = 0; dg < 4; ++dg) {
        Ot[st][dg] = __builtin_amdgcn_mfma_f32_16x16x32_bf16(vf[dg][0], pf0, Ot[st][dg], 0, 0, 0);
        Ot[st][dg] = __builtin_amdgcn_mfma_f32_16x16x32_bf16(vf[dg][1], pf1, Ot[st][dg], 0, 0, 0);
      }
    }
  }

  // epilogue: both strips
#pragma unroll
  for (int st = 0; st < 2; ++st) {
    const float rl = __builtin_amdgcn_rcpf(ls[st]);
    const int s = Rs[st] + lr;
#pragma unroll
    for (int dg = 0; dg < 4; ++dg) {
      const size_t o = ((size_t)b * S_LEN + s) * D_MODEL + h * 64 + dg * 16 + quad * 4;
      *(unsigned int*)&AO[o]     = pkbf(Ot[st][dg][0] * rl, Ot[st][dg][1] * rl);
      *(unsigned int*)&AO[o + 2] = pkbf(Ot[st][dg][2] * rl, Ot[st][dg][3] * rl);
    }
  }
}

extern "C" void kernel_launch(void* const* d_in, const int* in_sizes, int n_in,
                              void* d_out, int out_size, void* d_ws, size_t ws_size,
                              hipStream_t stream) {
  const float* x      = (const float*)d_in[0];
  const float* w_attn = (const float*)d_in[1];
  const float* b_attn = (const float*)d_in[2];
  const float* w_proj = (const float*)d_in[3];
  const float* b_proj = (const float*)d_in[4];
  float* out = (float*)d_out;

  unsigned short* ws     = (unsigned short*)d_ws;
  unsigned short* xb     = ws;                                   // 4096x1024
  unsigned short* wqkvT  = xb + (size_t)M_ROWS * D_MODEL;        // 3072x1024
  unsigned short* wprojT = wqkvT + (size_t)N_QKV * D_MODEL;      // 1024x1024
  unsigned short* Qb     = wprojT + (size_t)D_MODEL * D_MODEL;   // [B*H, S, hd] (pre-scaled)
  unsigned short* Kb     = Qb + (size_t)M_ROWS * D_MODEL;        // [B*H, S, hd]
  unsigned short* VT     = Kb + (size_t)M_ROWS * D_MODEL;        // [B*H, hd, S]
  unsigned short* AO     = xb;  // reuse: xb dead after QKV GEMM

  k_prep<<<8192, 256, 0, stream>>>(x, xb, w_attn, wqkvT, w_proj, wprojT);
  k_gemm_qkv<<<dim3(N_QKV / 128, M_ROWS / 128), 256, 0, stream>>>(xb, wqkvT, b_attn, Qb, Kb, VT);
  k_attn6<<<dim3(BATCH * NHEAD, 16), 256, 0, stream>>>(Qb, Kb, VT, AO);
  k_gemm_proj<<<dim3(D_MODEL / 128, M_ROWS / 128), 256, 0, stream>>>(AO, wprojT, b_proj, out);
}

// Round 6
// 179.883 us; speedup vs baseline: 1.6654x; 1.1088x over previous
//
#include <hip/hip_runtime.h>

#define S_LEN 2048
#define D_MODEL 1024
#define NHEAD 16
#define HDIM 64
#define BATCH 2
#define M_ROWS (BATCH * S_LEN)   // 4096
#define N_QKV (3 * D_MODEL)      // 3072
#define QSCALE 0.18033688011112042f  // 0.125 * log2(e)

typedef __attribute__((ext_vector_type(8))) short bf16x8;
typedef __attribute__((ext_vector_type(4))) float f32x4;

static __device__ __forceinline__ unsigned short f2bf(float f) {
  unsigned int u = __float_as_uint(f);
  u += 0x7FFFu + ((u >> 16) & 1u);   // RNE
  return (unsigned short)(u >> 16);
}
// pack two floats to bf16x2
static __device__ __forceinline__ unsigned int pkbf(float a, float b) {
  unsigned int ua = __float_as_uint(a) + 0x8000u;
  unsigned int ub = __float_as_uint(b) + 0x8000u;
  return __builtin_amdgcn_perm(ub, ua, 0x07060302u);
}

// async global->LDS 16B copy; effective LDS dst = wave-uniform base + lane*16
static __device__ __forceinline__ void async_cp16(unsigned short* lds, const unsigned short* g) {
  __builtin_amdgcn_global_load_lds((__attribute__((address_space(1))) void*)g,
                                   (__attribute__((address_space(3))) void*)lds, 16, 0, 0);
}

// ---------------- merged prep: cast x, transpose-cast both weights ----------------
__global__ __launch_bounds__(256) void k_prep(const float* __restrict__ x,
                                              unsigned short* __restrict__ xb,
                                              const float* __restrict__ w_attn,
                                              unsigned short* __restrict__ wqkvT,
                                              const float* __restrict__ w_proj,
                                              unsigned short* __restrict__ wprojT) {
  __shared__ unsigned short T[32][33];
  const int blk = blockIdx.x;
  const int tid = threadIdx.x;
  if (blk < 4096) {
    int i = blk * 256 + tid;
    float4 v = ((const float4*)x)[i];
    ushort4 o;
    o.x = f2bf(v.x); o.y = f2bf(v.y); o.z = f2bf(v.z); o.w = f2bf(v.w);
    ((ushort4*)xb)[i] = o;
    return;
  }
  const float* w;
  unsigned short* wT;
  int bid, Ndim;
  if (blk < 7168) { bid = blk - 4096; w = w_attn; wT = wqkvT; Ndim = N_QKV; }
  else            { bid = blk - 7168; w = w_proj; wT = wprojT; Ndim = D_MODEL; }
  const int nb = Ndim / 32;
  const int n0 = (bid % nb) * 32, k0 = (bid / nb) * 32;
  const int tx = tid & 31, ty = tid >> 5;
#pragma unroll
  for (int j = 0; j < 4; ++j) {
    int r = ty + j * 8;
    T[r][tx] = f2bf(w[(size_t)(k0 + r) * Ndim + n0 + tx]);
  }
  __syncthreads();
#pragma unroll
  for (int j = 0; j < 4; ++j) {
    int r = ty + j * 8;
    wT[(size_t)(n0 + r) * D_MODEL + k0 + tx] = T[tx][r];
  }
}

// ---------------- QKV GEMM: [4096,1024] x [1024,3072] + bias ----------------
// 1-D grid of 768 blocks. XCD swizzle: blk&7 -> 8x12-block region (A 2MB + B 3MB
// fits 4MB per-XCD L2). Ping-pong LDS: 1 barrier/iter, next tile's async loads
// issued after barrier -> full MFMA phase of global-latency overlap.
__global__ __launch_bounds__(256) void k_gemm_qkv(const unsigned short* __restrict__ A,
                                                  const unsigned short* __restrict__ Bt,
                                                  const float* __restrict__ bias,
                                                  unsigned short* __restrict__ Qb,
                                                  unsigned short* __restrict__ Kbuf,
                                                  unsigned short* __restrict__ VTb) {
  __shared__ __align__(16) unsigned short As[2][128 * 32];
  __shared__ __align__(16) unsigned short Bs[2][128 * 32];
  const int tid = threadIdx.x;
  const int wid = tid >> 6, lane = tid & 63;
  const int lr = lane & 15, lg = lane >> 4;
  const int blk = blockIdx.x;
  const int xcd = blk & 7, idx = blk >> 3;            // 96 blocks per XCD
  const int bm = ((xcd & 3) * 8 + (idx & 7)) * 128;   // rows: region of 8
  const int bn = ((xcd >> 2) * 12 + (idx >> 3)) * 128; // cols: region of 12
  const int wm = (wid >> 1) * 64, wn = (wid & 1) * 64;
  const int K = D_MODEL;
  const int c0 = tid, c1 = tid + 256;
  const size_t a0o = (size_t)(bm + (c0 >> 2)) * K + (c0 & 3) * 8;
  const size_t a1o = (size_t)(bm + (c1 >> 2)) * K + (c1 & 3) * 8;
  const size_t b0o = (size_t)(bn + (c0 >> 2)) * K + (c0 & 3) * 8;
  const size_t b1o = (size_t)(bn + (c1 >> 2)) * K + (c1 & 3) * 8;

  f32x4 acc[4][4] = {};

  // prologue: stage k=0 into buffer 0
  async_cp16(&As[0][c0 * 8], &A[a0o]);
  async_cp16(&As[0][c1 * 8], &A[a1o]);
  async_cp16(&Bs[0][c0 * 8], &Bt[b0o]);
  async_cp16(&Bs[0][c1 * 8], &Bt[b1o]);

  for (int k0 = 0; k0 < K; k0 += 32) {
    const int p = (k0 >> 5) & 1;
    __syncthreads();   // drains buf[p] loads; all waves done reading buf[p^1]
    if (k0 + 32 < K) {
      async_cp16(&As[p ^ 1][c0 * 8], &A[a0o + k0 + 32]);
      async_cp16(&As[p ^ 1][c1 * 8], &A[a1o + k0 + 32]);
      async_cp16(&Bs[p ^ 1][c0 * 8], &Bt[b0o + k0 + 32]);
      async_cp16(&Bs[p ^ 1][c1 * 8], &Bt[b1o + k0 + 32]);
    }
    bf16x8 af[4], bfr[4];
#pragma unroll
    for (int i = 0; i < 4; ++i) af[i] = *(const bf16x8*)&As[p][(wm + i * 16 + lr) * 32 + lg * 8];
#pragma unroll
    for (int t = 0; t < 4; ++t) bfr[t] = *(const bf16x8*)&Bs[p][(wn + t * 16 + lr) * 32 + lg * 8];
#pragma unroll
    for (int i = 0; i < 4; ++i)
#pragma unroll
      for (int t = 0; t < 4; ++t)
        acc[i][t] = __builtin_amdgcn_mfma_f32_16x16x32_bf16(af[i], bfr[t], acc[i][t], 0, 0, 0);
  }
#pragma unroll
  for (int i = 0; i < 4; ++i) {
#pragma unroll
    for (int t = 0; t < 4; ++t) {
      int n = bn + wn + t * 16 + lr;
      int part = n >> 10, rem = n & 1023;
      int h = rem >> 6, d = rem & 63;
      float bv = bias[n];
      int row0 = bm + wm + i * 16 + lg * 4;
      int bb = row0 >> 11, s0 = row0 & 2047;
      if (part == 2) {
        ushort4 vv;
        vv.x = f2bf(acc[i][t][0] + bv);
        vv.y = f2bf(acc[i][t][1] + bv);
        vv.z = f2bf(acc[i][t][2] + bv);
        vv.w = f2bf(acc[i][t][3] + bv);
        *(ushort4*)&VTb[(((size_t)(bb << 4) + h) * HDIM + d) * S_LEN + s0] = vv;
      } else {
        unsigned short* dst = (part == 0) ? Qb : Kbuf;
        float sc = (part == 0) ? QSCALE : 1.0f;
#pragma unroll
        for (int r = 0; r < 4; ++r)
          dst[(((size_t)(bb << 4) + h) * S_LEN + (s0 + r)) * HDIM + d] = f2bf((acc[i][t][r] + bv) * sc);
      }
    }
  }
}

// ---------------- Proj GEMM: [4096,1024] x [1024,1024] + bias -> fp32 ----------------
// 1-D grid of 256 blocks. XCD swizzle: blk&7 -> 4x8-block region (A 1MB + B 2MB).
__global__ __launch_bounds__(256) void k_gemm_proj(const unsigned short* __restrict__ A,
                                                   const unsigned short* __restrict__ Bt,
                                                   const float* __restrict__ bias,
                                                   float* __restrict__ out) {
  __shared__ __align__(16) unsigned short As[2][128 * 32];
  __shared__ __align__(16) unsigned short Bs[2][128 * 32];
  const int tid = threadIdx.x;
  const int wid = tid >> 6, lane = tid & 63;
  const int lr = lane & 15, lg = lane >> 4;
  const int blk = blockIdx.x;
  const int xcd = blk & 7, idx = blk >> 3;          // 32 blocks per XCD
  const int bm = (xcd * 4 + (idx & 3)) * 128;       // rows: region of 4
  const int bn = (idx >> 2) * 128;                  // cols: all 8
  const int wm = (wid >> 1) * 64, wn = (wid & 1) * 64;
  const int K = D_MODEL;
  const int c0 = tid, c1 = tid + 256;
  const size_t a0o = (size_t)(bm + (c0 >> 2)) * K + (c0 & 3) * 8;
  const size_t a1o = (size_t)(bm + (c1 >> 2)) * K + (c1 & 3) * 8;
  const size_t b0o = (size_t)(bn + (c0 >> 2)) * K + (c0 & 3) * 8;
  const size_t b1o = (size_t)(bn + (c1 >> 2)) * K + (c1 & 3) * 8;

  f32x4 acc[4][4] = {};

  async_cp16(&As[0][c0 * 8], &A[a0o]);
  async_cp16(&As[0][c1 * 8], &A[a1o]);
  async_cp16(&Bs[0][c0 * 8], &Bt[b0o]);
  async_cp16(&Bs[0][c1 * 8], &Bt[b1o]);

  for (int k0 = 0; k0 < K; k0 += 32) {
    const int p = (k0 >> 5) & 1;
    __syncthreads();
    if (k0 + 32 < K) {
      async_cp16(&As[p ^ 1][c0 * 8], &A[a0o + k0 + 32]);
      async_cp16(&As[p ^ 1][c1 * 8], &A[a1o + k0 + 32]);
      async_cp16(&Bs[p ^ 1][c0 * 8], &Bt[b0o + k0 + 32]);
      async_cp16(&Bs[p ^ 1][c1 * 8], &Bt[b1o + k0 + 32]);
    }
    bf16x8 af[4], bfr[4];
#pragma unroll
    for (int i = 0; i < 4; ++i) af[i] = *(const bf16x8*)&As[p][(wm + i * 16 + lr) * 32 + lg * 8];
#pragma unroll
    for (int t = 0; t < 4; ++t) bfr[t] = *(const bf16x8*)&Bs[p][(wn + t * 16 + lr) * 32 + lg * 8];
#pragma unroll
    for (int i = 0; i < 4; ++i)
#pragma unroll
      for (int t = 0; t < 4; ++t)
        acc[i][t] = __builtin_amdgcn_mfma_f32_16x16x32_bf16(af[i], bfr[t], acc[i][t], 0, 0, 0);
  }
#pragma unroll
  for (int i = 0; i < 4; ++i) {
#pragma unroll
    for (int t = 0; t < 4; ++t) {
      int n = bn + wn + t * 16 + lr;
      float bv = bias[n];
#pragma unroll
      for (int r = 0; r < 4; ++r) {
        int row = bm + wm + i * 16 + lg * 4 + r;
        out[(size_t)row * D_MODEL + n] = acc[i][t][r] + bv;
      }
    }
  }
}

// ---------------- Flash attention: block-cooperative LDS staging (round-5, unchanged) ----------------
__global__ __launch_bounds__(256, 2) void k_attn6(const unsigned short* __restrict__ Qb,
                                                  const unsigned short* __restrict__ Kb,
                                                  const unsigned short* __restrict__ VT,
                                                  unsigned short* __restrict__ AO) {
  const int tid = threadIdx.x;
  const int wid = tid >> 6, lane = tid & 63;
  const int lr = lane & 15, quad = lane >> 4;
  const int bh = blockIdx.x;                  // XCD pin: bh % 8
  const int slot = blockIdx.y;                // 0..15
  const int b = bh >> 4, h = bh & 15;

  __shared__ __align__(16) unsigned short Ks[64 * 64];
  __shared__ __align__(16) unsigned short Vs[64 * 64];
  __shared__ __align__(16) unsigned short Pbuf[4][16 * 72];
  unsigned short* pb = &Pbuf[wid][0];

  const unsigned short* Kbh = Kb + (size_t)bh * S_LEN * HDIM;
  const unsigned short* VTbh = VT + (size_t)bh * HDIM * S_LEN;

  const int sL = slot * 4 + wid;              // 0..63
  const int Rs[2] = {sL * 16, (127 - sL) * 16};
  const int ntile = ((127 - slot * 4) >> 2) + 1;

  bf16x8 qf[2][2];
#pragma unroll
  for (int st = 0; st < 2; ++st)
#pragma unroll
    for (int dh = 0; dh < 2; ++dh)
      qf[st][dh] = *(const bf16x8*)&Qb[((size_t)bh * S_LEN + Rs[st] + lr) * HDIM + dh * 32 + quad * 8];

  f32x4 Ot[2][4] = {};
  float ms[2] = {-1e30f, -1e30f};
  float ls[2] = {0.f, 0.f};

  const int srow = lane >> 3;
  const int scol = ((lane & 7) ^ srow) * 8;

  for (int kt = 0; kt < ntile; ++kt) {
    const int k0 = kt * 64;
    __syncthreads();
#pragma unroll
    for (int j = 0; j < 2; ++j) {
      const int r0 = wid * 16 + j * 8;
      async_cp16(&Ks[r0 * 64 + lane * 8], &Kbh[(size_t)(k0 + r0 + srow) * HDIM + scol]);
      async_cp16(&Vs[r0 * 64 + lane * 8], &VTbh[(size_t)(r0 + srow) * S_LEN + k0 + scol]);
    }
    __syncthreads();

    bf16x8 kf[4][2], vf[4][2];
#pragma unroll
    for (int kg = 0; kg < 4; ++kg)
#pragma unroll
      for (int dh = 0; dh < 2; ++dh)
        kf[kg][dh] = *(const bf16x8*)&Ks[(kg * 16 + lr) * 64 + (((dh * 4 + quad) ^ (lr & 7)) * 8)];
#pragma unroll
    for (int dg = 0; dg < 4; ++dg)
#pragma unroll
      for (int kh = 0; kh < 2; ++kh)
        vf[dg][kh] = *(const bf16x8*)&Vs[(dg * 16 + lr) * 64 + (((kh * 4 + quad) ^ (lr & 7)) * 8)];

#pragma unroll
    for (int st = 0; st < 2; ++st) {
      const int R = Rs[st];
      if (k0 > R + 15) continue;
      f32x4 Sv[4];
#pragma unroll
      for (int kg = 0; kg < 4; ++kg) {
        f32x4 a = {};
        a = __builtin_amdgcn_mfma_f32_16x16x32_bf16(kf[kg][0], qf[st][0], a, 0, 0, 0);
        a = __builtin_amdgcn_mfma_f32_16x16x32_bf16(kf[kg][1], qf[st][1], a, 0, 0, 0);
        Sv[kg] = a;
      }
      if (k0 + 63 > R) {
        const int q = R + lr;
#pragma unroll
        for (int kg = 0; kg < 4; ++kg)
#pragma unroll
          for (int r = 0; r < 4; ++r)
            if (k0 + kg * 16 + quad * 4 + r > q) Sv[kg][r] = -1e30f;
      }
      float mx = ms[st];
#pragma unroll
      for (int kg = 0; kg < 4; ++kg)
        mx = fmaxf(mx, fmaxf(fmaxf(Sv[kg][0], Sv[kg][1]), fmaxf(Sv[kg][2], Sv[kg][3])));
      mx = fmaxf(mx, __shfl_xor(mx, 16));
      mx = fmaxf(mx, __shfl_xor(mx, 32));
      const float alpha = __builtin_amdgcn_exp2f(ms[st] - mx);
      ms[st] = mx;
      float rs = 0.f;
#pragma unroll
      for (int kg = 0; kg < 4; ++kg) {
        float e0 = __builtin_amdgcn_exp2f(Sv[kg][0] - mx);
        float e1 = __builtin_amdgcn_exp2f(Sv[kg][1] - mx);
        float e2 = __builtin_amdgcn_exp2f(Sv[kg][2] - mx);
        float e3 = __builtin_amdgcn_exp2f(Sv[kg][3] - mx);
        rs += (e0 + e1) + (e2 + e3);
        *(unsigned int*)&pb[lr * 72 + kg * 16 + quad * 4]     = pkbf(e0, e1);
        *(unsigned int*)&pb[lr * 72 + kg * 16 + quad * 4 + 2] = pkbf(e2, e3);
      }
      rs += __shfl_xor(rs, 16);
      rs += __shfl_xor(rs, 32);
      ls[st] = ls[st] * alpha + rs;
#pragma unroll
      for (int dg = 0; dg < 4; ++dg)
#pragma unroll
        for (int r = 0; r < 4; ++r) Ot[st][dg][r] *= alpha;
      bf16x8 pf0 = *(const bf16x8*)&pb[lr * 72 + quad * 8];
      bf16x8 pf1 = *(const bf16x8*)&pb[lr * 72 + 32 + quad * 8];
#pragma unroll
      for (int dg = 0; dg < 4; ++dg) {
        Ot[st][dg] = __builtin_amdgcn_mfma_f32_16x16x32_bf16(vf[dg][0], pf0, Ot[st][dg], 0, 0, 0);
        Ot[st][dg] = __builtin_amdgcn_mfma_f32_16x16x32_bf16(vf[dg][1], pf1, Ot[st][dg], 0, 0, 0);
      }
    }
  }

#pragma unroll
  for (int st = 0; st < 2; ++st) {
    const float rl = __builtin_amdgcn_rcpf(ls[st]);
    const int s = Rs[st] + lr;
#pragma unroll
    for (int dg = 0; dg < 4; ++dg) {
      const size_t o = ((size_t)b * S_LEN + s) * D_MODEL + h * 64 + dg * 16 + quad * 4;
      *(unsigned int*)&AO[o]     = pkbf(Ot[st][dg][0] * rl, Ot[st][dg][1] * rl);
      *(unsigned int*)&AO[o + 2] = pkbf(Ot[st][dg][2] * rl, Ot[st][dg][3] * rl);
    }
  }
}

extern "C" void kernel_launch(void* const* d_in, const int* in_sizes, int n_in,
                              void* d_out, int out_size, void* d_ws, size_t ws_size,
                              hipStream_t stream) {
  const float* x      = (const float*)d_in[0];
  const float* w_attn = (const float*)d_in[1];
  const float* b_attn = (const float*)d_in[2];
  const float* w_proj = (const float*)d_in[3];
  const float* b_proj = (const float*)d_in[4];
  float* out = (float*)d_out;

  unsigned short* ws     = (unsigned short*)d_ws;
  unsigned short* xb     = ws;                                   // 4096x1024
  unsigned short* wqkvT  = xb + (size_t)M_ROWS * D_MODEL;        // 3072x1024
  unsigned short* wprojT = wqkvT + (size_t)N_QKV * D_MODEL;      // 1024x1024
  unsigned short* Qb     = wprojT + (size_t)D_MODEL * D_MODEL;   // [B*H, S, hd] (pre-scaled)
  unsigned short* Kb     = Qb + (size_t)M_ROWS * D_MODEL;        // [B*H, S, hd]
  unsigned short* VT     = Kb + (size_t)M_ROWS * D_MODEL;        // [B*H, hd, S]
  unsigned short* AO     = xb;  // reuse: xb dead after QKV GEMM

  k_prep<<<8192, 256, 0, stream>>>(x, xb, w_attn, wqkvT, w_proj, wprojT);
  k_gemm_qkv<<<768, 256, 0, stream>>>(xb, wqkvT, b_attn, Qb, Kb, VT);
  k_attn6<<<dim3(BATCH * NHEAD, 16), 256, 0, stream>>>(Qb, Kb, VT, AO);
  k_gemm_proj<<<256, 256, 0, stream>>>(AO, wprojT, b_proj, out);
}

// Round 7
// 179.702 us; speedup vs baseline: 1.6671x; 1.0010x over previous
//
#include <hip/hip_runtime.h>

#define S_LEN 2048
#define D_MODEL 1024
#define NHEAD 16
#define HDIM 64
#define BATCH 2
#define M_ROWS (BATCH * S_LEN)   // 4096
#define N_QKV (3 * D_MODEL)      // 3072
#define QSCALE 0.18033688011112042f  // 0.125 * log2(e)

typedef __attribute__((ext_vector_type(8))) short bf16x8;
typedef __attribute__((ext_vector_type(4))) float f32x4;

static __device__ __forceinline__ unsigned short f2bf(float f) {
  unsigned int u = __float_as_uint(f);
  u += 0x7FFFu + ((u >> 16) & 1u);   // RNE
  return (unsigned short)(u >> 16);
}
// pack two floats to bf16x2
static __device__ __forceinline__ unsigned int pkbf(float a, float b) {
  unsigned int ua = __float_as_uint(a) + 0x8000u;
  unsigned int ub = __float_as_uint(b) + 0x8000u;
  return __builtin_amdgcn_perm(ub, ua, 0x07060302u);
}

// async global->LDS 16B copy; effective LDS dst = wave-uniform base + lane*16
static __device__ __forceinline__ void async_cp16(unsigned short* lds, const unsigned short* g) {
  __builtin_amdgcn_global_load_lds((__attribute__((address_space(1))) void*)g,
                                   (__attribute__((address_space(3))) void*)lds, 16, 0, 0);
}

// ---------------- merged prep: cast x, transpose-cast both weights ----------------
__global__ __launch_bounds__(256) void k_prep(const float* __restrict__ x,
                                              unsigned short* __restrict__ xb,
                                              const float* __restrict__ w_attn,
                                              unsigned short* __restrict__ wqkvT,
                                              const float* __restrict__ w_proj,
                                              unsigned short* __restrict__ wprojT) {
  __shared__ unsigned short T[32][33];
  const int blk = blockIdx.x;
  const int tid = threadIdx.x;
  if (blk < 4096) {
    int i = blk * 256 + tid;
    float4 v = ((const float4*)x)[i];
    ushort4 o;
    o.x = f2bf(v.x); o.y = f2bf(v.y); o.z = f2bf(v.z); o.w = f2bf(v.w);
    ((ushort4*)xb)[i] = o;
    return;
  }
  const float* w;
  unsigned short* wT;
  int bid, Ndim;
  if (blk < 7168) { bid = blk - 4096; w = w_attn; wT = wqkvT; Ndim = N_QKV; }
  else            { bid = blk - 7168; w = w_proj; wT = wprojT; Ndim = D_MODEL; }
  const int nb = Ndim / 32;
  const int n0 = (bid % nb) * 32, k0 = (bid / nb) * 32;
  const int tx = tid & 31, ty = tid >> 5;
#pragma unroll
  for (int j = 0; j < 4; ++j) {
    int r = ty + j * 8;
    T[r][tx] = f2bf(w[(size_t)(k0 + r) * Ndim + n0 + tx]);
  }
  __syncthreads();
#pragma unroll
  for (int j = 0; j < 4; ++j) {
    int r = ty + j * 8;
    wT[(size_t)(n0 + r) * D_MODEL + k0 + tx] = T[tx][r];
  }
}

// ---------------- QKV GEMM: [4096,1024] x [1024,3072] + bias (round-6, unchanged) ----------------
__global__ __launch_bounds__(256) void k_gemm_qkv(const unsigned short* __restrict__ A,
                                                  const unsigned short* __restrict__ Bt,
                                                  const float* __restrict__ bias,
                                                  unsigned short* __restrict__ Qb,
                                                  unsigned short* __restrict__ Kbuf,
                                                  unsigned short* __restrict__ VTb) {
  __shared__ __align__(16) unsigned short As[2][128 * 32];
  __shared__ __align__(16) unsigned short Bs[2][128 * 32];
  const int tid = threadIdx.x;
  const int wid = tid >> 6, lane = tid & 63;
  const int lr = lane & 15, lg = lane >> 4;
  const int blk = blockIdx.x;
  const int xcd = blk & 7, idx = blk >> 3;
  const int bm = ((xcd & 3) * 8 + (idx & 7)) * 128;
  const int bn = ((xcd >> 2) * 12 + (idx >> 3)) * 128;
  const int wm = (wid >> 1) * 64, wn = (wid & 1) * 64;
  const int K = D_MODEL;
  const int c0 = tid, c1 = tid + 256;
  const size_t a0o = (size_t)(bm + (c0 >> 2)) * K + (c0 & 3) * 8;
  const size_t a1o = (size_t)(bm + (c1 >> 2)) * K + (c1 & 3) * 8;
  const size_t b0o = (size_t)(bn + (c0 >> 2)) * K + (c0 & 3) * 8;
  const size_t b1o = (size_t)(bn + (c1 >> 2)) * K + (c1 & 3) * 8;

  f32x4 acc[4][4] = {};

  async_cp16(&As[0][c0 * 8], &A[a0o]);
  async_cp16(&As[0][c1 * 8], &A[a1o]);
  async_cp16(&Bs[0][c0 * 8], &Bt[b0o]);
  async_cp16(&Bs[0][c1 * 8], &Bt[b1o]);

  for (int k0 = 0; k0 < K; k0 += 32) {
    const int p = (k0 >> 5) & 1;
    __syncthreads();
    if (k0 + 32 < K) {
      async_cp16(&As[p ^ 1][c0 * 8], &A[a0o + k0 + 32]);
      async_cp16(&As[p ^ 1][c1 * 8], &A[a1o + k0 + 32]);
      async_cp16(&Bs[p ^ 1][c0 * 8], &Bt[b0o + k0 + 32]);
      async_cp16(&Bs[p ^ 1][c1 * 8], &Bt[b1o + k0 + 32]);
    }
    bf16x8 af[4], bfr[4];
#pragma unroll
    for (int i = 0; i < 4; ++i) af[i] = *(const bf16x8*)&As[p][(wm + i * 16 + lr) * 32 + lg * 8];
#pragma unroll
    for (int t = 0; t < 4; ++t) bfr[t] = *(const bf16x8*)&Bs[p][(wn + t * 16 + lr) * 32 + lg * 8];
#pragma unroll
    for (int i = 0; i < 4; ++i)
#pragma unroll
      for (int t = 0; t < 4; ++t)
        acc[i][t] = __builtin_amdgcn_mfma_f32_16x16x32_bf16(af[i], bfr[t], acc[i][t], 0, 0, 0);
  }
#pragma unroll
  for (int i = 0; i < 4; ++i) {
#pragma unroll
    for (int t = 0; t < 4; ++t) {
      int n = bn + wn + t * 16 + lr;
      int part = n >> 10, rem = n & 1023;
      int h = rem >> 6, d = rem & 63;
      float bv = bias[n];
      int row0 = bm + wm + i * 16 + lg * 4;
      int bb = row0 >> 11, s0 = row0 & 2047;
      if (part == 2) {
        ushort4 vv;
        vv.x = f2bf(acc[i][t][0] + bv);
        vv.y = f2bf(acc[i][t][1] + bv);
        vv.z = f2bf(acc[i][t][2] + bv);
        vv.w = f2bf(acc[i][t][3] + bv);
        *(ushort4*)&VTb[(((size_t)(bb << 4) + h) * HDIM + d) * S_LEN + s0] = vv;
      } else {
        unsigned short* dst = (part == 0) ? Qb : Kbuf;
        float sc = (part == 0) ? QSCALE : 1.0f;
#pragma unroll
        for (int r = 0; r < 4; ++r)
          dst[(((size_t)(bb << 4) + h) * S_LEN + (s0 + r)) * HDIM + d] = f2bf((acc[i][t][r] + bv) * sc);
      }
    }
  }
}

// ---------------- Proj GEMM: [4096,1024] x [1024,1024] + bias -> fp32 (round-6, unchanged) ----------------
__global__ __launch_bounds__(256) void k_gemm_proj(const unsigned short* __restrict__ A,
                                                   const unsigned short* __restrict__ Bt,
                                                   const float* __restrict__ bias,
                                                   float* __restrict__ out) {
  __shared__ __align__(16) unsigned short As[2][128 * 32];
  __shared__ __align__(16) unsigned short Bs[2][128 * 32];
  const int tid = threadIdx.x;
  const int wid = tid >> 6, lane = tid & 63;
  const int lr = lane & 15, lg = lane >> 4;
  const int blk = blockIdx.x;
  const int xcd = blk & 7, idx = blk >> 3;
  const int bm = (xcd * 4 + (idx & 3)) * 128;
  const int bn = (idx >> 2) * 128;
  const int wm = (wid >> 1) * 64, wn = (wid & 1) * 64;
  const int K = D_MODEL;
  const int c0 = tid, c1 = tid + 256;
  const size_t a0o = (size_t)(bm + (c0 >> 2)) * K + (c0 & 3) * 8;
  const size_t a1o = (size_t)(bm + (c1 >> 2)) * K + (c1 & 3) * 8;
  const size_t b0o = (size_t)(bn + (c0 >> 2)) * K + (c0 & 3) * 8;
  const size_t b1o = (size_t)(bn + (c1 >> 2)) * K + (c1 & 3) * 8;

  f32x4 acc[4][4] = {};

  async_cp16(&As[0][c0 * 8], &A[a0o]);
  async_cp16(&As[0][c1 * 8], &A[a1o]);
  async_cp16(&Bs[0][c0 * 8], &Bt[b0o]);
  async_cp16(&Bs[0][c1 * 8], &Bt[b1o]);

  for (int k0 = 0; k0 < K; k0 += 32) {
    const int p = (k0 >> 5) & 1;
    __syncthreads();
    if (k0 + 32 < K) {
      async_cp16(&As[p ^ 1][c0 * 8], &A[a0o + k0 + 32]);
      async_cp16(&As[p ^ 1][c1 * 8], &A[a1o + k0 + 32]);
      async_cp16(&Bs[p ^ 1][c0 * 8], &Bt[b0o + k0 + 32]);
      async_cp16(&Bs[p ^ 1][c1 * 8], &Bt[b1o + k0 + 32]);
    }
    bf16x8 af[4], bfr[4];
#pragma unroll
    for (int i = 0; i < 4; ++i) af[i] = *(const bf16x8*)&As[p][(wm + i * 16 + lr) * 32 + lg * 8];
#pragma unroll
    for (int t = 0; t < 4; ++t) bfr[t] = *(const bf16x8*)&Bs[p][(wn + t * 16 + lr) * 32 + lg * 8];
#pragma unroll
    for (int i = 0; i < 4; ++i)
#pragma unroll
      for (int t = 0; t < 4; ++t)
        acc[i][t] = __builtin_amdgcn_mfma_f32_16x16x32_bf16(af[i], bfr[t], acc[i][t], 0, 0, 0);
  }
#pragma unroll
  for (int i = 0; i < 4; ++i) {
#pragma unroll
    for (int t = 0; t < 4; ++t) {
      int n = bn + wn + t * 16 + lr;
      float bv = bias[n];
#pragma unroll
      for (int r = 0; r < 4; ++r) {
        int row = bm + wm + i * 16 + lg * 4 + r;
        out[(size_t)row * D_MODEL + n] = acc[i][t][r] + bv;
      }
    }
  }
}

// ---------------- Flash attention round 7: ping-pong staging + makespan pairing ----------------
// Ping-pong K/V LDS double-buffer: ONE barrier per 64-key tile; next tile's
// global_load_lds issued right after the barrier -> a full compute phase of
// latency overlap before its drain (mirrors the qkv GEMM round-6 win).
// 1-D grid of 512: block i and i+256 (same CU under round-robin) carry slots
// a and 15-a -> per-CU tile sum (32-a)+(17+a)=49, constant. bh=blk&31 keeps
// the XCD pin (blk%8 == bh%8).
__global__ __launch_bounds__(256, 2) void k_attn7(const unsigned short* __restrict__ Qb,
                                                  const unsigned short* __restrict__ Kb,
                                                  const unsigned short* __restrict__ VT,
                                                  unsigned short* __restrict__ AO) {
  const int tid = threadIdx.x;
  const int wid = tid >> 6, lane = tid & 63;
  const int lr = lane & 15, quad = lane >> 4;
  const int blk = blockIdx.x;
  const int bh = blk & 31;
  const int g = blk >> 5;                     // 0..15
  const int slot = (g < 8) ? g : 23 - g;      // pair a with 15-a across grid halves
  const int b = bh >> 4, h = bh & 15;

  __shared__ __align__(16) unsigned short Ks[2][64 * 64];
  __shared__ __align__(16) unsigned short Vs[2][64 * 64];
  __shared__ __align__(16) unsigned short Pbuf[4][16 * 72];
  unsigned short* pb = &Pbuf[wid][0];

  const unsigned short* Kbh = Kb + (size_t)bh * S_LEN * HDIM;
  const unsigned short* VTbh = VT + (size_t)bh * HDIM * S_LEN;

  const int sL = slot * 4 + wid;              // 0..63
  const int Rs[2] = {sL * 16, (127 - sL) * 16};
  const int ntile = ((127 - slot * 4) >> 2) + 1;   // == 32 - slot

  bf16x8 qf[2][2];
#pragma unroll
  for (int st = 0; st < 2; ++st)
#pragma unroll
    for (int dh = 0; dh < 2; ++dh)
      qf[st][dh] = *(const bf16x8*)&Qb[((size_t)bh * S_LEN + Rs[st] + lr) * HDIM + dh * 32 + quad * 8];

  f32x4 Ot[2][4] = {};
  float ms[2] = {-1e30f, -1e30f};
  float ls[2] = {0.f, 0.f};

  const int srow = lane >> 3;                 // 0..7
  const int scol = ((lane & 7) ^ srow) * 8;   // xor-swizzled 16B block

  // prologue: stage tile 0 into buffer 0
#pragma unroll
  for (int j = 0; j < 2; ++j) {
    const int r0 = wid * 16 + j * 8;
    async_cp16(&Ks[0][r0 * 64 + lane * 8], &Kbh[(size_t)(r0 + srow) * HDIM + scol]);
    async_cp16(&Vs[0][r0 * 64 + lane * 8], &VTbh[(size_t)(r0 + srow) * S_LEN + scol]);
  }

  for (int kt = 0; kt < ntile; ++kt) {
    const int k0 = kt * 64;
    const int p = kt & 1;
    __syncthreads();   // drains buf[p] staging; all waves done reading buf[p^1]
    if (kt + 1 < ntile) {
      const int kn = k0 + 64;
#pragma unroll
      for (int j = 0; j < 2; ++j) {
        const int r0 = wid * 16 + j * 8;
        async_cp16(&Ks[p ^ 1][r0 * 64 + lane * 8], &Kbh[(size_t)(kn + r0 + srow) * HDIM + scol]);
        async_cp16(&Vs[p ^ 1][r0 * 64 + lane * 8], &VTbh[(size_t)(r0 + srow) * S_LEN + kn + scol]);
      }
    }

    bf16x8 kf[4][2], vf[4][2];
#pragma unroll
    for (int kg = 0; kg < 4; ++kg)
#pragma unroll
      for (int dh = 0; dh < 2; ++dh)
        kf[kg][dh] = *(const bf16x8*)&Ks[p][(kg * 16 + lr) * 64 + (((dh * 4 + quad) ^ (lr & 7)) * 8)];
#pragma unroll
    for (int dg = 0; dg < 4; ++dg)
#pragma unroll
      for (int kh = 0; kh < 2; ++kh)
        vf[dg][kh] = *(const bf16x8*)&Vs[p][(dg * 16 + lr) * 64 + (((kh * 4 + quad) ^ (lr & 7)) * 8)];

#pragma unroll
    for (int st = 0; st < 2; ++st) {
      const int R = Rs[st];
      if (k0 > R + 15) continue;    // strip finished (wave-uniform)
      f32x4 Sv[4];
#pragma unroll
      for (int kg = 0; kg < 4; ++kg) {
        f32x4 a = {};
        a = __builtin_amdgcn_mfma_f32_16x16x32_bf16(kf[kg][0], qf[st][0], a, 0, 0, 0);
        a = __builtin_amdgcn_mfma_f32_16x16x32_bf16(kf[kg][1], qf[st][1], a, 0, 0, 0);
        Sv[kg] = a;
      }
      if (k0 + 63 > R) {            // diagonal tile: causal mask
        const int q = R + lr;
#pragma unroll
        for (int kg = 0; kg < 4; ++kg)
#pragma unroll
          for (int r = 0; r < 4; ++r)
            if (k0 + kg * 16 + quad * 4 + r > q) Sv[kg][r] = -1e30f;
      }
      float mx = ms[st];
#pragma unroll
      for (int kg = 0; kg < 4; ++kg)
        mx = fmaxf(mx, fmaxf(fmaxf(Sv[kg][0], Sv[kg][1]), fmaxf(Sv[kg][2], Sv[kg][3])));
      mx = fmaxf(mx, __shfl_xor(mx, 16));
      mx = fmaxf(mx, __shfl_xor(mx, 32));
      const float alpha = __builtin_amdgcn_exp2f(ms[st] - mx);
      ms[st] = mx;
      float rs = 0.f;
#pragma unroll
      for (int kg = 0; kg < 4; ++kg) {
        float e0 = __builtin_amdgcn_exp2f(Sv[kg][0] - mx);
        float e1 = __builtin_amdgcn_exp2f(Sv[kg][1] - mx);
        float e2 = __builtin_amdgcn_exp2f(Sv[kg][2] - mx);
        float e3 = __builtin_amdgcn_exp2f(Sv[kg][3] - mx);
        rs += (e0 + e1) + (e2 + e3);
        *(unsigned int*)&pb[lr * 72 + kg * 16 + quad * 4]     = pkbf(e0, e1);
        *(unsigned int*)&pb[lr * 72 + kg * 16 + quad * 4 + 2] = pkbf(e2, e3);
      }
      rs += __shfl_xor(rs, 16);
      rs += __shfl_xor(rs, 32);
      ls[st] = ls[st] * alpha + rs;
#pragma unroll
      for (int dg = 0; dg < 4; ++dg)
#pragma unroll
        for (int r = 0; r < 4; ++r) Ot[st][dg][r] *= alpha;
      bf16x8 pf0 = *(const bf16x8*)&pb[lr * 72 + quad * 8];
      bf16x8 pf1 = *(const bf16x8*)&pb[lr * 72 + 32 + quad * 8];
#pragma unroll
      for (int dg = 0; dg < 4; ++dg) {
        Ot[st][dg] = __builtin_amdgcn_mfma_f32_16x16x32_bf16(vf[dg][0], pf0, Ot[st][dg], 0, 0, 0);
        Ot[st][dg] = __builtin_amdgcn_mfma_f32_16x16x32_bf16(vf[dg][1], pf1, Ot[st][dg], 0, 0, 0);
      }
    }
  }

#pragma unroll
  for (int st = 0; st < 2; ++st) {
    const float rl = __builtin_amdgcn_rcpf(ls[st]);
    const int s = Rs[st] + lr;
#pragma unroll
    for (int dg = 0; dg < 4; ++dg) {
      const size_t o = ((size_t)b * S_LEN + s) * D_MODEL + h * 64 + dg * 16 + quad * 4;
      *(unsigned int*)&AO[o]     = pkbf(Ot[st][dg][0] * rl, Ot[st][dg][1] * rl);
      *(unsigned int*)&AO[o + 2] = pkbf(Ot[st][dg][2] * rl, Ot[st][dg][3] * rl);
    }
  }
}

extern "C" void kernel_launch(void* const* d_in, const int* in_sizes, int n_in,
                              void* d_out, int out_size, void* d_ws, size_t ws_size,
                              hipStream_t stream) {
  const float* x      = (const float*)d_in[0];
  const float* w_attn = (const float*)d_in[1];
  const float* b_attn = (const float*)d_in[2];
  const float* w_proj = (const float*)d_in[3];
  const float* b_proj = (const float*)d_in[4];
  float* out = (float*)d_out;

  unsigned short* ws     = (unsigned short*)d_ws;
  unsigned short* xb     = ws;                                   // 4096x1024
  unsigned short* wqkvT  = xb + (size_t)M_ROWS * D_MODEL;        // 3072x1024
  unsigned short* wprojT = wqkvT + (size_t)N_QKV * D_MODEL;      // 1024x1024
  unsigned short* Qb     = wprojT + (size_t)D_MODEL * D_MODEL;   // [B*H, S, hd] (pre-scaled)
  unsigned short* Kb     = Qb + (size_t)M_ROWS * D_MODEL;        // [B*H, S, hd]
  unsigned short* VT     = Kb + (size_t)M_ROWS * D_MODEL;        // [B*H, hd, S]
  unsigned short* AO     = xb;  // reuse: xb dead after QKV GEMM

  k_prep<<<8192, 256, 0, stream>>>(x, xb, w_attn, wqkvT, w_proj, wprojT);
  k_gemm_qkv<<<768, 256, 0, stream>>>(xb, wqkvT, b_attn, Qb, Kb, VT);
  k_attn7<<<512, 256, 0, stream>>>(Qb, Kb, VT, AO);
  k_gemm_proj<<<256, 256, 0, stream>>>(AO, wprojT, b_proj, out);
}